// Round 2
// baseline (4660.609 us; speedup 1.0000x reference)
//
#include <hip/hip_runtime.h>

#define BB 128
#define SS 256
#define WW 20
#define WE 300
#define CE 50
#define CC 100
#define DIN 400
#define HID 512
#define Hh 256
#define TT 12
#define START_TAG 9
#define STOP_TAG 10
#define PAD_TAG 11
#define NEGV (-10000.0f)
#define BS 32768   // BB*SS
#define CH 32      // timesteps per chunk
#define NCH 8      // SS/CH
#define CR 4096    // CH*BB rows per direction per chunk

// ---------------- Kernel A: embed one chunk's rows (both dir ranges) ----------------
// grid 4096 blocks, 256 thr; each block does 2 positions of the 8192 chunk rows.
__global__ __launch_bounds__(256) void k_embedC(
    const int* __restrict__ widx, const int* __restrict__ cidx,
    const float* __restrict__ wtab, const float* __restrict__ ctab,
    const float* __restrict__ convw, const float* __restrict__ convb,
    float* __restrict__ embC, int c)
{
    __shared__ __align__(16) float ce_sh[2][CE][24];  // [pos][ce][w+1], zero edges
    __shared__ int cid_sh[2][WW];
    __shared__ int wid_sh[2];
    const int tid = threadIdx.x;
    const int pl0 = blockIdx.x * 2;   // chunk-local position 0..8190

    // per-position chunk-local -> (part, lr, s, b, g)
    int part[2], lr[2], g[2];
    #pragma unroll
    for (int p = 0; p < 2; p++) {
        int pl = pl0 + p;
        part[p] = pl >> 12;           // 0 fwd, 1 bwd
        lr[p] = pl & 4095;            // ls*BB + b
        int ls = lr[p] >> 7;
        int b = lr[p] & 127;
        int s = part[p] ? (224 - 32 * c + ls) : (32 * c + ls);
        g[p] = b * SS + s;            // (B,S) index for widx/cidx
    }

    if (tid < 2 * WW) {
        int p = tid / WW, w = tid % WW;
        cid_sh[p][w] = cidx[g[p] * WW + w];
    }
    if (tid < 2) wid_sh[tid] = widx[g[tid]];
    for (int i = tid; i < 2 * CE * 24; i += 256) ((float*)ce_sh)[i] = 0.f;
    __syncthreads();

    for (int i = tid; i < 2 * WW * CE; i += 256) {
        int p = i / (WW * CE);
        int rem = i % (WW * CE);
        int w = rem / CE, ce = rem % CE;
        ce_sh[p][ce][w + 1] = ctab[cid_sh[p][w] * CE + ce];
    }
    for (int i = tid; i < 2 * WE; i += 256) {
        int p = i / WE, col = i % WE;
        embC[(size_t)(part[p] * CR + lr[p]) * DIN + col] =
            wtab[(size_t)wid_sh[p] * WE + col];
    }
    __syncthreads();

    const int p = tid >> 7;
    const int cc = tid & 127;
    if (cc < CC) {
        float acc[WW];
        #pragma unroll
        for (int w = 0; w < WW; w++) acc[w] = 0.f;
        for (int ce = 0; ce < CE; ce++) {
            float row[24];
            #pragma unroll
            for (int q = 0; q < 6; q++) {
                float4 v = *(const float4*)&ce_sh[p][ce][q * 4];
                row[q * 4 + 0] = v.x; row[q * 4 + 1] = v.y;
                row[q * 4 + 2] = v.z; row[q * 4 + 3] = v.w;
            }
            float c0 = convw[(cc * CE + ce) * 3 + 0];
            float c1 = convw[(cc * CE + ce) * 3 + 1];
            float c2 = convw[(cc * CE + ce) * 3 + 2];
            #pragma unroll
            for (int w = 0; w < WW; w++)
                acc[w] += c0 * row[w] + c1 * row[w + 1] + c2 * row[w + 2];
        }
        float bb = convb[cc];
        float m = 0.f;  // relu >= 0 so max >= 0
        #pragma unroll
        for (int w = 0; w < WW; w++) {
            float v = acc[w] + bb;
            v = v > 0.f ? v : 0.f;
            m = v > m ? v : m;
        }
        embC[(size_t)(part[p] * CR + lr[p]) * DIN + WE + cc] = m;
    }
}

// ---------------- Kernel B: chunk input projection: gatesC(2048 x 4096) ----------------
// grid (32 rtiles, 16 jtiles) x 256 thr; 128x128 tile, 8x8 microtile.
__global__ __launch_bounds__(256) void k_projC(
    const float* __restrict__ embC,
    const float* __restrict__ wih_f, const float* __restrict__ wih_b,
    const float* __restrict__ bih_f, const float* __restrict__ bhh_f,
    const float* __restrict__ bih_b, const float* __restrict__ bhh_b,
    float* __restrict__ gatesC)
{
    __shared__ __align__(16) float As[8][132];
    __shared__ __align__(16) float Bs[8][132];
    const int tid = threadIdx.x;
    const int rt = blockIdx.x;   // 0..31
    const int jt = blockIdx.y;   // 0..15
    const int tx = tid & 15, ty = tid >> 4;
    const int lj = tid >> 1;
    const int kh = (tid & 1) * 4;

    float acc[8][8];
    #pragma unroll
    for (int i = 0; i < 8; i++)
        #pragma unroll
        for (int j = 0; j < 8; j++) acc[i][j] = 0.f;

    const int jg = jt * 128 + lj;          // 0..2047
    const float* wsrc = (jg < 1024) ? wih_f : wih_b;
    const int jj = jg & 1023;
    const int dirpart = jt >> 3;           // j<1024 -> fwd rows, else bwd rows
    const float* esrc = embC + (size_t)dirpart * CR * DIN;

    for (int k0 = 0; k0 < DIN; k0 += 8) {
        float4 av = *(const float4*)&wsrc[(size_t)jj * DIN + k0 + kh];
        float4 bv = *(const float4*)&esrc[(size_t)(rt * 128 + lj) * DIN + k0 + kh];
        __syncthreads();
        As[kh + 0][lj] = av.x; As[kh + 1][lj] = av.y; As[kh + 2][lj] = av.z; As[kh + 3][lj] = av.w;
        Bs[kh + 0][lj] = bv.x; Bs[kh + 1][lj] = bv.y; Bs[kh + 2][lj] = bv.z; Bs[kh + 3][lj] = bv.w;
        __syncthreads();
        #pragma unroll
        for (int kk = 0; kk < 8; kk++) {
            float4 a0 = *(const float4*)&As[kk][ty * 8];
            float4 a1 = *(const float4*)&As[kk][ty * 8 + 4];
            float4 b0 = *(const float4*)&Bs[kk][tx * 8];
            float4 b1 = *(const float4*)&Bs[kk][tx * 8 + 4];
            float aa[8] = {a0.x, a0.y, a0.z, a0.w, a1.x, a1.y, a1.z, a1.w};
            float bbv[8] = {b0.x, b0.y, b0.z, b0.w, b1.x, b1.y, b1.z, b1.w};
            #pragma unroll
            for (int i = 0; i < 8; i++)
                #pragma unroll
                for (int j = 0; j < 8; j++) acc[i][j] += aa[i] * bbv[j];
        }
    }

    #pragma unroll
    for (int i = 0; i < 8; i++) {
        int j = jt * 128 + ty * 8 + i;
        int dir = j >> 10;
        int jr = j & 1023;
        float bias = dir ? (bih_b[jr] + bhh_b[jr]) : (bih_f[jr] + bhh_f[jr]);
        size_t base = (size_t)j * CR + rt * 128 + tx * 8;
        float4 o0 = {acc[i][0] + bias, acc[i][1] + bias, acc[i][2] + bias, acc[i][3] + bias};
        float4 o1 = {acc[i][4] + bias, acc[i][5] + bias, acc[i][6] + bias, acc[i][7] + bias};
        *(float4*)&gatesC[base] = o0;
        *(float4*)&gatesC[base + 4] = o1;
    }
}

// ---------------- Kernel C: one LSTM time step, both directions ----------------
// grid 256: blk = dir*128 + kslice. threads 256: tid = klo*128 + b.
__global__ __launch_bounds__(256) void k_step(
    const float* __restrict__ gatesC,
    const float* __restrict__ whh_f, const float* __restrict__ whh_b,
    float* __restrict__ hbuf, float* __restrict__ cbuf, float* __restrict__ lstmC,
    int t)
{
    const int tid = threadIdx.x;
    const int b = tid & 127;
    const int klo = tid >> 7;
    const int blk = blockIdx.x;
    const int dir = blk >> 7;
    const int ksl = blk & 127;
    const int kg = ksl * 2 + klo;
    const int tl = t & (CH - 1);
    const int lr = (dir ? (CH - 1 - tl) : tl) * BB + b;

    const float* whh = dir ? whh_b : whh_f;
    const int kgs = __builtin_amdgcn_readfirstlane(kg);
    const float* w0 = whh + (size_t)(0 * Hh + kgs) * Hh;
    const float* w1 = whh + (size_t)(1 * Hh + kgs) * Hh;
    const float* w2 = whh + (size_t)(2 * Hh + kgs) * Hh;
    const float* w3 = whh + (size_t)(3 * Hh + kgs) * Hh;

    const int jb = dir * 1024;
    float g0 = gatesC[(size_t)(jb + 0 * Hh + kg) * CR + lr];
    float g1 = gatesC[(size_t)(jb + 1 * Hh + kg) * CR + lr];
    float g2 = gatesC[(size_t)(jb + 2 * Hh + kg) * CR + lr];
    float g3 = gatesC[(size_t)(jb + 3 * Hh + kg) * CR + lr];

    if (t > 0) {
        const int par = t & 1;
        const float* hsrc = hbuf + (size_t)((par * 2 + dir) * Hh) * BB;  // [k][b]
        #pragma unroll 2
        for (int kk = 0; kk < Hh; kk += 4) {
            float h0 = hsrc[(kk + 0) * BB + b];
            float h1 = hsrc[(kk + 1) * BB + b];
            float h2 = hsrc[(kk + 2) * BB + b];
            float h3 = hsrc[(kk + 3) * BB + b];
            float4 wa = *(const float4*)&w0[kk];
            float4 wb = *(const float4*)&w1[kk];
            float4 wc = *(const float4*)&w2[kk];
            float4 wd = *(const float4*)&w3[kk];
            g0 += h0 * wa.x + h1 * wa.y + h2 * wa.z + h3 * wa.w;
            g1 += h0 * wb.x + h1 * wb.y + h2 * wb.z + h3 * wb.w;
            g2 += h0 * wc.x + h1 * wc.y + h2 * wc.z + h3 * wc.w;
            g3 += h0 * wd.x + h1 * wd.y + h2 * wd.z + h3 * wd.w;
        }
    }

    float c_old = (t > 0) ? cbuf[(size_t)(dir * Hh + kg) * BB + b] : 0.f;
    float si = 1.f / (1.f + expf(-g0));
    float sf = 1.f / (1.f + expf(-g1));
    float tg = tanhf(g2);
    float so = 1.f / (1.f + expf(-g3));
    float c_new = sf * c_old + si * tg;
    float h_new = so * tanhf(c_new);

    cbuf[(size_t)(dir * Hh + kg) * BB + b] = c_new;
    const int parn = (t + 1) & 1;
    hbuf[(size_t)((parn * 2 + dir) * Hh + kg) * BB + b] = h_new;
    lstmC[(size_t)(dir * Hh + kg) * CR + lr] = h_new;
}

// ---------------- Kernel D0: feats = bias ----------------
__global__ __launch_bounds__(256) void k_feats_init(
    const float* __restrict__ h2b, float* __restrict__ feats)
{
    int i = blockIdx.x * 256 + threadIdx.x;
    if (i < BS * TT) feats[i] = h2b[i % TT];
}

// ---------------- Kernel D: accumulate chunk's lstm h into feats ----------------
// grid 64 (2 parts x 32 ls), 128 thr (b).
__global__ __launch_bounds__(128) void k_feats_acc(
    const float* __restrict__ lstmC,
    const float* __restrict__ h2w, float* __restrict__ feats, int c)
{
    const int part = blockIdx.x >> 5;
    const int ls = blockIdx.x & 31;
    const int b = threadIdx.x;
    const int s = part ? (224 - 32 * c + ls) : (32 * c + ls);
    const int r = s * BB + b;

    float acc[TT];
    #pragma unroll
    for (int t = 0; t < TT; t++) acc[t] = 0.f;
    for (int dk = 0; dk < Hh; dk++) {
        float v = lstmC[(size_t)(part * Hh + dk) * CR + ls * BB + b];
        #pragma unroll
        for (int t = 0; t < TT; t++) acc[t] += v * h2w[t * HID + part * Hh + dk];
    }
    #pragma unroll
    for (int t = 0; t < TT; t++) feats[(size_t)r * TT + t] += acc[t];
}

// ---------------- Kernel E: Viterbi forward + backtrace, one wave per batch ----------------
__global__ __launch_bounds__(64) void k_viterbi(
    const float* __restrict__ feats,
    const int* __restrict__ mask, const float* __restrict__ trans,
    float* __restrict__ out)
{
    __shared__ unsigned char bp_sh[SS][TT];
    __shared__ int red[64];
    __shared__ int len_sh;
    const int b = blockIdx.x;
    const int tid = threadIdx.x;
    const int n = tid;

    int partial = 0;
    for (int s = tid; s < SS; s += 64) partial += mask[b * SS + s];
    red[tid] = partial;
    __syncthreads();
    if (tid == 0) {
        int L = 0;
        for (int i = 0; i < 64; i++) L += red[i];
        len_sh = L;
    }
    __syncthreads();
    const int len = len_sh;

    float tr[TT];
    float alpha = NEGV;
    if (n < TT) {
        #pragma unroll
        for (int p = 0; p < TT; p++) tr[p] = trans[p * TT + n];
        alpha = (n == START_TAG) ? 0.f : NEGV;
    }

    for (int s = 0; s < len; s++) {
        float feat = (n < TT) ? feats[(size_t)(s * BB + b) * TT + n] : 0.f;
        float best = -3.0e38f;
        int bpi = 0;
        #pragma unroll
        for (int p = 0; p < TT; p++) {
            float ap = __shfl(alpha, p, 64);
            float sc = (n < TT) ? ((ap + tr[p]) + feat) : -3.0e38f;
            if (sc > best) { best = sc; bpi = p; }
        }
        if (n < TT) {
            bp_sh[s][n] = (unsigned char)bpi;
            alpha = best;
        }
    }

    float term = (n < TT) ? (alpha + trans[STOP_TAG * TT + n]) : -3.0e38f;
    float bs = -3.0e38f;
    int bl = 0;
    #pragma unroll
    for (int p = 0; p < TT; p++) {
        float v = __shfl(term, p, 64);
        if (v > bs) { bs = v; bl = p; }
    }

    if (tid == 0) {
        out[b] = bs;
        int tag = bl;
        for (int s = SS - 1; s >= 0; s--) {
            float o;
            if (s < len) {
                o = (float)tag;
                tag = (int)bp_sh[s][tag];
            } else {
                o = (float)PAD_TAG;
            }
            out[BB + b * SS + s] = o;
        }
    }
}

extern "C" void kernel_launch(void* const* d_in, const int* in_sizes, int n_in,
                              void* d_out, int out_size, void* d_ws, size_t ws_size,
                              hipStream_t stream) {
    const int*   widx  = (const int*)d_in[0];
    const int*   cidx  = (const int*)d_in[1];
    const int*   mask  = (const int*)d_in[2];
    const float* wtab  = (const float*)d_in[3];
    const float* ctab  = (const float*)d_in[4];
    const float* convw = (const float*)d_in[5];
    const float* convb = (const float*)d_in[6];
    const float* wih_f = (const float*)d_in[7];
    const float* whh_f = (const float*)d_in[8];
    const float* bih_f = (const float*)d_in[9];
    const float* bhh_f = (const float*)d_in[10];
    const float* wih_b = (const float*)d_in[11];
    const float* whh_b = (const float*)d_in[12];
    const float* bih_b = (const float*)d_in[13];
    const float* bhh_b = (const float*)d_in[14];
    const float* h2w   = (const float*)d_in[15];
    const float* h2b   = (const float*)d_in[16];
    const float* trans = (const float*)d_in[17];

    float* ws = (float*)d_ws;
    float* embC   = ws;                                    // 2*4096*400      = 3,276,800
    float* gatesC = embC + (size_t)2 * CR * DIN;           // 2048*4096       = 8,388,608
    float* lstmC  = gatesC + (size_t)2048 * CR;            // 512*4096        = 2,097,152
    float* feats  = lstmC + (size_t)HID * CR;              // 32768*12        =   393,216
    float* hbuf   = feats + (size_t)BS * TT;               // 2*2*256*128     =   131,072
    float* cbuf   = hbuf + (size_t)4 * Hh * BB;            // 2*256*128       =    65,536
    // total 14,352,384 floats = 54.75 MiB

    hipLaunchKernelGGL(k_feats_init, dim3((BS * TT + 255) / 256), dim3(256), 0, stream,
                       h2b, feats);
    for (int c = 0; c < NCH; c++) {
        hipLaunchKernelGGL(k_embedC, dim3(CR / 2 * 2 / 2), dim3(256), 0, stream,
                           widx, cidx, wtab, ctab, convw, convb, embC, c);
        hipLaunchKernelGGL(k_projC, dim3(CR / 128, 16), dim3(256), 0, stream,
                           embC, wih_f, wih_b, bih_f, bhh_f, bih_b, bhh_b, gatesC);
        for (int tl = 0; tl < CH; tl++) {
            hipLaunchKernelGGL(k_step, dim3(256), dim3(256), 0, stream,
                               gatesC, whh_f, whh_b, hbuf, cbuf, lstmC, c * CH + tl);
        }
        hipLaunchKernelGGL(k_feats_acc, dim3(64), dim3(128), 0, stream,
                           lstmC, h2w, feats, c);
    }
    hipLaunchKernelGGL(k_viterbi, dim3(BB), dim3(64), 0, stream, feats, mask, trans, (float*)d_out);
}

// Round 3
// 3417.194 us; speedup vs baseline: 1.3639x; 1.3639x over previous
//
#include <hip/hip_runtime.h>

#define BB 128
#define SS 256
#define WW 20
#define WE 300
#define CE 50
#define CC 100
#define DIN 400
#define HID 512
#define Hh 256
#define TT 12
#define START_TAG 9
#define STOP_TAG 10
#define PAD_TAG 11
#define NEGV (-10000.0f)
#define BS 32768   // BB*SS
#define CH 32      // timesteps per chunk
#define NCH 8      // SS/CH
#define CR 4096    // CH*BB rows per direction per chunk

// ws bytes needed for full-emb mode: (13107200+8388608+2097152+393216+131072+65536)*4
#define FULL_NEEDED_BYTES 96731136ull

// ---------------- Kernel A-full: embed entire sequence, each position ONCE ----------------
// grid 16384 x 256 thr; block does 2 positions pl = s*BB+b.
__global__ __launch_bounds__(256) void k_embedF(
    const int* __restrict__ widx, const int* __restrict__ cidx,
    const float* __restrict__ wtab, const float* __restrict__ ctab,
    const float* __restrict__ convw, const float* __restrict__ convb,
    float* __restrict__ emb)
{
    __shared__ __align__(16) float ce_sh[2][CE][24];
    __shared__ int cid_sh[2][WW];
    __shared__ int wid_sh[2];
    const int tid = threadIdx.x;
    const int pl0 = blockIdx.x * 2;

    int g[2];
    #pragma unroll
    for (int p = 0; p < 2; p++) {
        int pl = pl0 + p;
        int s = pl >> 7, b = pl & 127;
        g[p] = b * SS + s;
    }

    if (tid < 2 * WW) {
        int p = tid / WW, w = tid % WW;
        cid_sh[p][w] = cidx[g[p] * WW + w];
    }
    if (tid < 2) wid_sh[tid] = widx[g[tid]];
    for (int i = tid; i < 2 * CE * 24; i += 256) ((float*)ce_sh)[i] = 0.f;
    __syncthreads();

    for (int i = tid; i < 2 * WW * CE; i += 256) {
        int p = i / (WW * CE);
        int rem = i % (WW * CE);
        int w = rem / CE, ce = rem % CE;
        ce_sh[p][ce][w + 1] = ctab[cid_sh[p][w] * CE + ce];
    }
    for (int i = tid; i < 2 * WE; i += 256) {
        int p = i / WE, col = i % WE;
        emb[(size_t)(pl0 + p) * DIN + col] = wtab[(size_t)wid_sh[p] * WE + col];
    }
    __syncthreads();

    const int p = tid >> 7;
    const int cc = tid & 127;
    if (cc < CC) {
        float acc[WW];
        #pragma unroll
        for (int w = 0; w < WW; w++) acc[w] = 0.f;
        for (int ce = 0; ce < CE; ce++) {
            float row[24];
            #pragma unroll
            for (int q = 0; q < 6; q++) {
                float4 v = *(const float4*)&ce_sh[p][ce][q * 4];
                row[q * 4 + 0] = v.x; row[q * 4 + 1] = v.y;
                row[q * 4 + 2] = v.z; row[q * 4 + 3] = v.w;
            }
            float c0 = convw[(cc * CE + ce) * 3 + 0];
            float c1 = convw[(cc * CE + ce) * 3 + 1];
            float c2 = convw[(cc * CE + ce) * 3 + 2];
            #pragma unroll
            for (int w = 0; w < WW; w++)
                acc[w] += c0 * row[w] + c1 * row[w + 1] + c2 * row[w + 2];
        }
        float bb = convb[cc];
        float m = 0.f;
        #pragma unroll
        for (int w = 0; w < WW; w++) {
            float v = acc[w] + bb;
            v = v > 0.f ? v : 0.f;
            m = v > m ? v : m;
        }
        emb[(size_t)(pl0 + p) * DIN + WE + cc] = m;
    }
}

// ---------------- Kernel A-chunk: round-2 fallback (embed chunk rows, both dir ranges) ----------------
__global__ __launch_bounds__(256) void k_embedC(
    const int* __restrict__ widx, const int* __restrict__ cidx,
    const float* __restrict__ wtab, const float* __restrict__ ctab,
    const float* __restrict__ convw, const float* __restrict__ convb,
    float* __restrict__ embC, int c)
{
    __shared__ __align__(16) float ce_sh[2][CE][24];
    __shared__ int cid_sh[2][WW];
    __shared__ int wid_sh[2];
    const int tid = threadIdx.x;
    const int pl0 = blockIdx.x * 2;

    int part[2], lr[2], g[2];
    #pragma unroll
    for (int p = 0; p < 2; p++) {
        int pl = pl0 + p;
        part[p] = pl >> 12;
        lr[p] = pl & 4095;
        int ls = lr[p] >> 7;
        int b = lr[p] & 127;
        int s = part[p] ? (224 - 32 * c + ls) : (32 * c + ls);
        g[p] = b * SS + s;
    }

    if (tid < 2 * WW) {
        int p = tid / WW, w = tid % WW;
        cid_sh[p][w] = cidx[g[p] * WW + w];
    }
    if (tid < 2) wid_sh[tid] = widx[g[tid]];
    for (int i = tid; i < 2 * CE * 24; i += 256) ((float*)ce_sh)[i] = 0.f;
    __syncthreads();

    for (int i = tid; i < 2 * WW * CE; i += 256) {
        int p = i / (WW * CE);
        int rem = i % (WW * CE);
        int w = rem / CE, ce = rem % CE;
        ce_sh[p][ce][w + 1] = ctab[cid_sh[p][w] * CE + ce];
    }
    for (int i = tid; i < 2 * WE; i += 256) {
        int p = i / WE, col = i % WE;
        embC[(size_t)(part[p] * CR + lr[p]) * DIN + col] =
            wtab[(size_t)wid_sh[p] * WE + col];
    }
    __syncthreads();

    const int p = tid >> 7;
    const int cc = tid & 127;
    if (cc < CC) {
        float acc[WW];
        #pragma unroll
        for (int w = 0; w < WW; w++) acc[w] = 0.f;
        for (int ce = 0; ce < CE; ce++) {
            float row[24];
            #pragma unroll
            for (int q = 0; q < 6; q++) {
                float4 v = *(const float4*)&ce_sh[p][ce][q * 4];
                row[q * 4 + 0] = v.x; row[q * 4 + 1] = v.y;
                row[q * 4 + 2] = v.z; row[q * 4 + 3] = v.w;
            }
            float c0 = convw[(cc * CE + ce) * 3 + 0];
            float c1 = convw[(cc * CE + ce) * 3 + 1];
            float c2 = convw[(cc * CE + ce) * 3 + 2];
            #pragma unroll
            for (int w = 0; w < WW; w++)
                acc[w] += c0 * row[w] + c1 * row[w + 1] + c2 * row[w + 2];
        }
        float bb = convb[cc];
        float m = 0.f;
        #pragma unroll
        for (int w = 0; w < WW; w++) {
            float v = acc[w] + bb;
            v = v > 0.f ? v : 0.f;
            m = v > m ? v : m;
        }
        embC[(size_t)(part[p] * CR + lr[p]) * DIN + WE + cc] = m;
    }
}

// ---------------- Kernel B: chunk input projection: gatesC(2048 x 4096) ----------------
// ef: base of 4096 fwd rows; eb: base of 4096 bwd rows (row-major DIN).
__global__ __launch_bounds__(256) void k_projC(
    const float* __restrict__ ef, const float* __restrict__ eb,
    const float* __restrict__ wih_f, const float* __restrict__ wih_b,
    const float* __restrict__ bih_f, const float* __restrict__ bhh_f,
    const float* __restrict__ bih_b, const float* __restrict__ bhh_b,
    float* __restrict__ gatesC)
{
    __shared__ __align__(16) float As[8][132];
    __shared__ __align__(16) float Bs[8][132];
    const int tid = threadIdx.x;
    const int rt = blockIdx.x;   // 0..31
    const int jt = blockIdx.y;   // 0..15
    const int tx = tid & 15, ty = tid >> 4;
    const int lj = tid >> 1;
    const int kh = (tid & 1) * 4;

    float acc[8][8];
    #pragma unroll
    for (int i = 0; i < 8; i++)
        #pragma unroll
        for (int j = 0; j < 8; j++) acc[i][j] = 0.f;

    const int jg = jt * 128 + lj;
    const float* wsrc = (jg < 1024) ? wih_f : wih_b;
    const int jj = jg & 1023;
    const float* esrc = (jt >= 8) ? eb : ef;

    for (int k0 = 0; k0 < DIN; k0 += 8) {
        float4 av = *(const float4*)&wsrc[(size_t)jj * DIN + k0 + kh];
        float4 bv = *(const float4*)&esrc[(size_t)(rt * 128 + lj) * DIN + k0 + kh];
        __syncthreads();
        As[kh + 0][lj] = av.x; As[kh + 1][lj] = av.y; As[kh + 2][lj] = av.z; As[kh + 3][lj] = av.w;
        Bs[kh + 0][lj] = bv.x; Bs[kh + 1][lj] = bv.y; Bs[kh + 2][lj] = bv.z; Bs[kh + 3][lj] = bv.w;
        __syncthreads();
        #pragma unroll
        for (int kk = 0; kk < 8; kk++) {
            float4 a0 = *(const float4*)&As[kk][ty * 8];
            float4 a1 = *(const float4*)&As[kk][ty * 8 + 4];
            float4 b0 = *(const float4*)&Bs[kk][tx * 8];
            float4 b1 = *(const float4*)&Bs[kk][tx * 8 + 4];
            float aa[8] = {a0.x, a0.y, a0.z, a0.w, a1.x, a1.y, a1.z, a1.w};
            float bbv[8] = {b0.x, b0.y, b0.z, b0.w, b1.x, b1.y, b1.z, b1.w};
            #pragma unroll
            for (int i = 0; i < 8; i++)
                #pragma unroll
                for (int j = 0; j < 8; j++) acc[i][j] += aa[i] * bbv[j];
        }
    }

    #pragma unroll
    for (int i = 0; i < 8; i++) {
        int j = jt * 128 + ty * 8 + i;
        int dir = j >> 10;
        int jr = j & 1023;
        float bias = dir ? (bih_b[jr] + bhh_b[jr]) : (bih_f[jr] + bhh_f[jr]);
        size_t base = (size_t)j * CR + rt * 128 + tx * 8;
        float4 o0 = {acc[i][0] + bias, acc[i][1] + bias, acc[i][2] + bias, acc[i][3] + bias};
        float4 o1 = {acc[i][4] + bias, acc[i][5] + bias, acc[i][6] + bias, acc[i][7] + bias};
        *(float4*)&gatesC[base] = o0;
        *(float4*)&gatesC[base + 4] = o1;
    }
}

// ---------------- Kernel C: one LSTM step. grid 512 = dir*256+kg; thr 256 = (kh,b) ----------------
// kh halves the k-dot (each h element loaded once per block); LDS combine; 2 blocks/CU.
__global__ __launch_bounds__(256) void k_step2(
    const float* __restrict__ gatesC,
    const float* __restrict__ whh_f, const float* __restrict__ whh_b,
    float* __restrict__ hbuf, float* __restrict__ cbuf, float* __restrict__ lstmC,
    int t)
{
    __shared__ float psum[4][128];
    const int tid = threadIdx.x;
    const int b = tid & 127;
    const int kh = tid >> 7;
    const int blk = blockIdx.x;
    const int dir = blk >> 8;
    const int kg = blk & 255;
    const int tl = t & (CH - 1);
    const int lr = (dir ? (CH - 1 - tl) : tl) * BB + b;

    // preload input-projected gates + c_old early (hide latency under the dot loop)
    float q0 = 0.f, q1 = 0.f, q2 = 0.f, q3 = 0.f, c_old = 0.f;
    const int jb = dir * 1024;
    if (kh == 0) {
        q0 = gatesC[(size_t)(jb + 0 * Hh + kg) * CR + lr];
        q1 = gatesC[(size_t)(jb + 1 * Hh + kg) * CR + lr];
        q2 = gatesC[(size_t)(jb + 2 * Hh + kg) * CR + lr];
        q3 = gatesC[(size_t)(jb + 3 * Hh + kg) * CR + lr];
        if (t > 0) c_old = cbuf[(size_t)(dir * Hh + kg) * BB + b];
    }

    float g0 = 0.f, g1 = 0.f, g2 = 0.f, g3 = 0.f;
    if (t > 0) {
        const float* whh = dir ? whh_b : whh_f;
        const int koff = __builtin_amdgcn_readfirstlane(kh * 128);  // wave-uniform
        const float* w0 = whh + (size_t)(0 * Hh + kg) * Hh + koff;
        const float* w1 = whh + (size_t)(1 * Hh + kg) * Hh + koff;
        const float* w2 = whh + (size_t)(2 * Hh + kg) * Hh + koff;
        const float* w3 = whh + (size_t)(3 * Hh + kg) * Hh + koff;
        const int par = t & 1;
        const float* hsrc = hbuf + (size_t)((par * 2 + dir) * Hh + koff) * BB;  // [k][b]
        #pragma unroll 4
        for (int kk = 0; kk < 128; kk += 4) {
            float h0 = hsrc[(kk + 0) * BB + b];
            float h1 = hsrc[(kk + 1) * BB + b];
            float h2 = hsrc[(kk + 2) * BB + b];
            float h3 = hsrc[(kk + 3) * BB + b];
            float4 wa = *(const float4*)&w0[kk];
            float4 wb = *(const float4*)&w1[kk];
            float4 wc = *(const float4*)&w2[kk];
            float4 wd = *(const float4*)&w3[kk];
            g0 += h0 * wa.x + h1 * wa.y + h2 * wa.z + h3 * wa.w;
            g1 += h0 * wb.x + h1 * wb.y + h2 * wb.z + h3 * wb.w;
            g2 += h0 * wc.x + h1 * wc.y + h2 * wc.z + h3 * wc.w;
            g3 += h0 * wd.x + h1 * wd.y + h2 * wd.z + h3 * wd.w;
        }
    }

    if (kh) {
        psum[0][b] = g0; psum[1][b] = g1; psum[2][b] = g2; psum[3][b] = g3;
    }
    __syncthreads();
    if (!kh) {
        g0 = (q0 + g0) + psum[0][b];
        g1 = (q1 + g1) + psum[1][b];
        g2 = (q2 + g2) + psum[2][b];
        g3 = (q3 + g3) + psum[3][b];

        float si = 1.f / (1.f + expf(-g0));
        float sf = 1.f / (1.f + expf(-g1));
        float tg = tanhf(g2);
        float so = 1.f / (1.f + expf(-g3));
        float c_new = sf * c_old + si * tg;
        float h_new = so * tanhf(c_new);

        cbuf[(size_t)(dir * Hh + kg) * BB + b] = c_new;
        const int parn = (t + 1) & 1;
        hbuf[(size_t)((parn * 2 + dir) * Hh + kg) * BB + b] = h_new;
        lstmC[(size_t)(dir * Hh + kg) * CR + lr] = h_new;
    }
}

// ---------------- Kernel D0: feats = bias ----------------
__global__ __launch_bounds__(256) void k_feats_init(
    const float* __restrict__ h2b, float* __restrict__ feats)
{
    int i = blockIdx.x * 256 + threadIdx.x;
    if (i < BS * TT) feats[i] = h2b[i % TT];
}

// ---------------- Kernel D: accumulate chunk's lstm h into feats ----------------
// grid 64 (2 parts x 32 ls), 256 thr (kh,b); kh-split + LDS combine.
__global__ __launch_bounds__(256) void k_feats_acc(
    const float* __restrict__ lstmC,
    const float* __restrict__ h2w, float* __restrict__ feats, int c)
{
    __shared__ float ps[TT][128];
    const int part = blockIdx.x >> 5;
    const int ls = blockIdx.x & 31;
    const int b = threadIdx.x & 127;
    const int kh = threadIdx.x >> 7;
    const int s = part ? (224 - 32 * c + ls) : (32 * c + ls);
    const int r = s * BB + b;
    const int k0 = kh * 128;

    float acc[TT];
    #pragma unroll
    for (int t = 0; t < TT; t++) acc[t] = 0.f;
    for (int dk = 0; dk < 128; dk++) {
        float v = lstmC[(size_t)(part * Hh + k0 + dk) * CR + ls * BB + b];
        #pragma unroll
        for (int t = 0; t < TT; t++) acc[t] += v * h2w[t * HID + part * Hh + k0 + dk];
    }
    if (kh) {
        #pragma unroll
        for (int t = 0; t < TT; t++) ps[t][b] = acc[t];
    }
    __syncthreads();
    if (!kh) {
        #pragma unroll
        for (int t = 0; t < TT; t++)
            feats[(size_t)r * TT + t] += acc[t] + ps[t][b];
    }
}

// ---------------- Kernel E: Viterbi forward + backtrace, one wave per batch ----------------
__global__ __launch_bounds__(64) void k_viterbi(
    const float* __restrict__ feats,
    const int* __restrict__ mask, const float* __restrict__ trans,
    float* __restrict__ out)
{
    __shared__ unsigned char bp_sh[SS][TT];
    __shared__ int red[64];
    __shared__ int len_sh;
    const int b = blockIdx.x;
    const int tid = threadIdx.x;
    const int n = tid;

    int partial = 0;
    for (int s = tid; s < SS; s += 64) partial += mask[b * SS + s];
    red[tid] = partial;
    __syncthreads();
    if (tid == 0) {
        int L = 0;
        for (int i = 0; i < 64; i++) L += red[i];
        len_sh = L;
    }
    __syncthreads();
    const int len = len_sh;

    float tr[TT];
    float alpha = NEGV;
    if (n < TT) {
        #pragma unroll
        for (int p = 0; p < TT; p++) tr[p] = trans[p * TT + n];
        alpha = (n == START_TAG) ? 0.f : NEGV;
    }

    for (int s = 0; s < len; s++) {
        float feat = (n < TT) ? feats[(size_t)(s * BB + b) * TT + n] : 0.f;
        float best = -3.0e38f;
        int bpi = 0;
        #pragma unroll
        for (int p = 0; p < TT; p++) {
            float ap = __shfl(alpha, p, 64);
            float sc = (n < TT) ? ((ap + tr[p]) + feat) : -3.0e38f;
            if (sc > best) { best = sc; bpi = p; }
        }
        if (n < TT) {
            bp_sh[s][n] = (unsigned char)bpi;
            alpha = best;
        }
    }

    float term = (n < TT) ? (alpha + trans[STOP_TAG * TT + n]) : -3.0e38f;
    float bs = -3.0e38f;
    int bl = 0;
    #pragma unroll
    for (int p = 0; p < TT; p++) {
        float v = __shfl(term, p, 64);
        if (v > bs) { bs = v; bl = p; }
    }

    if (tid == 0) {
        out[b] = bs;
        int tag = bl;
        for (int s = SS - 1; s >= 0; s--) {
            float o;
            if (s < len) {
                o = (float)tag;
                tag = (int)bp_sh[s][tag];
            } else {
                o = (float)PAD_TAG;
            }
            out[BB + b * SS + s] = o;
        }
    }
}

extern "C" void kernel_launch(void* const* d_in, const int* in_sizes, int n_in,
                              void* d_out, int out_size, void* d_ws, size_t ws_size,
                              hipStream_t stream) {
    const int*   widx  = (const int*)d_in[0];
    const int*   cidx  = (const int*)d_in[1];
    const int*   mask  = (const int*)d_in[2];
    const float* wtab  = (const float*)d_in[3];
    const float* ctab  = (const float*)d_in[4];
    const float* convw = (const float*)d_in[5];
    const float* convb = (const float*)d_in[6];
    const float* wih_f = (const float*)d_in[7];
    const float* whh_f = (const float*)d_in[8];
    const float* bih_f = (const float*)d_in[9];
    const float* bhh_f = (const float*)d_in[10];
    const float* wih_b = (const float*)d_in[11];
    const float* whh_b = (const float*)d_in[12];
    const float* bih_b = (const float*)d_in[13];
    const float* bhh_b = (const float*)d_in[14];
    const float* h2w   = (const float*)d_in[15];
    const float* h2b   = (const float*)d_in[16];
    const float* trans = (const float*)d_in[17];

    const bool full = ws_size >= FULL_NEEDED_BYTES;  // constant per session -> same work each call
    float* ws = (float*)d_ws;
    float* emb    = ws;   // full: 32768*400 (52.4MB); chunk: 2*4096*400 (13.1MB)
    const size_t emb_fl = full ? (size_t)BS * DIN : (size_t)2 * CR * DIN;
    float* gatesC = emb + emb_fl;                    // 2048*4096
    float* lstmC  = gatesC + (size_t)2048 * CR;      // 512*4096
    float* feats  = lstmC + (size_t)HID * CR;        // 32768*12
    float* hbuf   = feats + (size_t)BS * TT;         // 2*2*256*128 (parity ping-pong)
    float* cbuf   = hbuf + (size_t)4 * Hh * BB;      // 2*256*128

    hipLaunchKernelGGL(k_feats_init, dim3((BS * TT + 255) / 256), dim3(256), 0, stream,
                       h2b, feats);
    if (full) {
        hipLaunchKernelGGL(k_embedF, dim3(BS / 2), dim3(256), 0, stream,
                           widx, cidx, wtab, ctab, convw, convb, emb);
    }
    for (int c = 0; c < NCH; c++) {
        if (!full) {
            hipLaunchKernelGGL(k_embedC, dim3(CR), dim3(256), 0, stream,
                               widx, cidx, wtab, ctab, convw, convb, emb, c);
        }
        const float* ef = full ? (emb + (size_t)(32 * c * BB) * DIN) : emb;
        const float* eb = full ? (emb + (size_t)((224 - 32 * c) * BB) * DIN)
                               : (emb + (size_t)CR * DIN);
        hipLaunchKernelGGL(k_projC, dim3(CR / 128, 16), dim3(256), 0, stream,
                           ef, eb, wih_f, wih_b, bih_f, bhh_f, bih_b, bhh_b, gatesC);
        for (int tl = 0; tl < CH; tl++) {
            hipLaunchKernelGGL(k_step2, dim3(512), dim3(256), 0, stream,
                               gatesC, whh_f, whh_b, hbuf, cbuf, lstmC, c * CH + tl);
        }
        hipLaunchKernelGGL(k_feats_acc, dim3(64), dim3(256), 0, stream,
                           lstmC, h2w, feats, c);
    }
    hipLaunchKernelGGL(k_viterbi, dim3(BB), dim3(64), 0, stream, feats, mask, trans, (float*)d_out);
}